// Round 21
// baseline (27.155 us; speedup 1.0000x reference)
//
#include <hip/hip_runtime.h>

#define BB 8
#define NN 256
#define DD 128
#define LN_EPS 1e-5f

// ---------------------------------------------------------------------------
// k_proj: hi = x @ w1[:D],  hjb = x @ w1[D:] + b1
// grid 256 blocks (8 rows) x 1024 threads (16 waves/CU = 4/SIMD).
// __launch_bounds__(1024,1): grid==CU count -> 1 block/CU regardless, so the
// relaxed bound costs nothing and removes the 64-VGPR cap.
// ---------------------------------------------------------------------------
__global__ __launch_bounds__(1024, 1) void k_proj(const float* __restrict__ x,
                                                  const float* __restrict__ w1,
                                                  const float* __restrict__ b1,
                                                  float* __restrict__ hi,
                                                  float* __restrict__ hjb) {
    __shared__ float xs[8 * DD];       // 4 KB
    __shared__ float part[16384];      // 64 KB: A @0, B @8192
    const int bid  = blockIdx.x;
    const int row0 = (bid & 7) * NN + (bid >> 3) * 8;   // XCD-affine
    const int tid  = threadIdx.x;
    xs[tid] = x[row0 * DD + tid];      // 1024 = 8*128 exactly
    __syncthreads();

    const int dp = tid & 127;
    const int kg = tid >> 7;     // 0..7
    const int kb = kg * 16;

    float aA[8] = {}, aB[8] = {};
    #pragma unroll
    for (int k4 = 0; k4 < 4; ++k4) {
        const int k0 = kb + k4 * 4;
        float wa[4], wb[4];
        #pragma unroll
        for (int q = 0; q < 4; ++q) {
            wa[q] = w1[(k0 + q) * DD + dp];
            wb[q] = w1[(DD + k0 + q) * DD + dp];
        }
        #pragma unroll
        for (int r = 0; r < 8; ++r) {
            const float4 xv = *(const float4*)&xs[r * DD + k0];  // broadcast
            aA[r] = fmaf(xv.x, wa[0], aA[r]);
            aA[r] = fmaf(xv.y, wa[1], aA[r]);
            aA[r] = fmaf(xv.z, wa[2], aA[r]);
            aA[r] = fmaf(xv.w, wa[3], aA[r]);
            aB[r] = fmaf(xv.x, wb[0], aB[r]);
            aB[r] = fmaf(xv.y, wb[1], aB[r]);
            aB[r] = fmaf(xv.z, wb[2], aB[r]);
            aB[r] = fmaf(xv.w, wb[3], aB[r]);
        }
    }
    #pragma unroll
    for (int r = 0; r < 8; ++r) {
        part[kg * 1024 + r * DD + dp]        = aA[r];
        part[8192 + kg * 1024 + r * DD + dp] = aB[r];
    }
    __syncthreads();
    {
        int r = tid >> 7, d = tid & 127;
        float sa = 0.f, sb = 0.f;
        #pragma unroll
        for (int w = 0; w < 8; ++w) {
            sa += part[w * 1024 + r * DD + d];
            sb += part[8192 + w * 1024 + r * DD + d];
        }
        hi [(row0 + r) * DD + d] = sa;
        hjb[(row0 + r) * DD + d] = sb + b1[d];
    }
}

// ---------------------------------------------------------------------------
// k_fused: R20 structure with __launch_bounds__(1024,1) — removes the
// 64-VGPR cap that spilled R20's pair accumulators (grid 256 = 1 block/CU
// anyway, so occupancy is unchanged at 16 waves/CU).
// Pair: a_tt[256][8] (1 b128 = 4 rows' a), 4 rows x 4 d per thread, 16-way
// j-split; pair LDS wave-instrs 2048 -> 512. Two-phase partial commit.
// Tail: 1 col/thread, 8-way k-split (R19 verbatim).
// ---------------------------------------------------------------------------
__global__ __launch_bounds__(1024, 1) void k_fused(const float* __restrict__ adj,
                                                   const float* __restrict__ x,
                                                   const float* __restrict__ hi,
                                                   const float* __restrict__ hjb,
                                                   const float* __restrict__ w2,
                                                   const float* __restrict__ b2,
                                                   const float* __restrict__ w3,
                                                   const float* __restrict__ b3,
                                                   const float* __restrict__ w4,
                                                   const float* __restrict__ b4,
                                                   const float* __restrict__ g,
                                                   const float* __restrict__ bet,
                                                   float* __restrict__ out) {
    __shared__ float smem[13352];
    float* const hjs    = smem;           // [64][128]
    float* const partP  = smem;           // [8][1024] alias
    float* const partT  = smem;           // [8][1024] alias
    float* const a_tt   = smem + 8192;    // [256][8]
    float* const u1s    = smem + 8192;    // [8][128] alias (a_tt dead)
    float* const resS   = smem + 9216;    // [8][128] alias
    float* const xs     = smem + 10240;   // [8][128]
    float* const ssp    = smem + 11264;   // [8][128]
    float* const aggs   = smem + 12288;   // [8][128]
    float* const asub   = smem + 13312;   // [8][4]
    float* const asum_s = smem + 13344;   // [8]

    const int bid  = blockIdx.x;
    const int b    = bid & 7;             // XCD-affine batch
    const int i0   = (bid >> 3) * 8;
    const int tid  = threadIdx.x;
    const int lane = tid & 63;
    const int wv   = tid >> 6;            // 0..15

    // ---- stage transposed masked adjacency + asum partials via shfl
    #pragma unroll
    for (int t = 0; t < 2; ++t) {
        int idx = tid + t * 1024;           // 0..2047
        int il = idx >> 8, j = idx & 255;   // il wave-uniform
        int ig = i0 + il;
        float av = adj[((size_t)b * NN + ig) * NN + j];
        av = (j == ig) ? 0.f : av;
        a_tt[j * 8 + il] = av;
        float s = av;
        #pragma unroll
        for (int m = 32; m; m >>= 1) s += __shfl_xor(s, m);
        if (lane == 0) asub[il * 4 + ((idx >> 6) & 3)] = s;
    }
    // ---- stage x rows
    xs[tid] = x[((size_t)b * NN + i0) * DD + tid];

    // ---- per-thread hi fragments: 4 rows x 4 d
    const int dq = lane & 31;        // d-quad (d0 = dq*4)
    const int rh = lane >> 5;        // rows rh*4 .. rh*4+3
    float4 hi4[4];
    #pragma unroll
    for (int rr = 0; rr < 4; ++rr)
        hi4[rr] = *(const float4*)&hi[((size_t)b * NN + i0 + rh * 4 + rr) * DD + dq * 4];
    float4 acc[4] = {{0,0,0,0},{0,0,0,0},{0,0,0,0},{0,0,0,0}};

    // ---- pair: 4 tiles of 64 j; wave wv covers j [wv*4, wv*4+4) per tile
    for (int jt = 0; jt < 4; ++jt) {
        __syncthreads();   // staging visible / prev tile reads done
        const float4* src = (const float4*)(hjb + ((size_t)b * NN + jt * 64) * DD);
        float4* dst = (float4*)hjs;
        #pragma unroll
        for (int t = 0; t < 2; ++t) dst[tid + t * 1024] = src[tid + t * 1024];
        __syncthreads();
        const int jb = wv * 4;
        #pragma unroll
        for (int jj = 0; jj < 4; ++jj) {
            const int jl = jb + jj;
            const float4 hv = *(const float4*)&hjs[jl * DD + dq * 4];
            const float4 a4 = *(const float4*)&a_tt[(jt * 64 + jl) * 8 + rh * 4];
            const float aa[4] = {a4.x, a4.y, a4.z, a4.w};
            #pragma unroll
            for (int rr = 0; rr < 4; ++rr) {
                acc[rr].x = fmaf(fmaxf(hi4[rr].x + hv.x, 0.f), aa[rr], acc[rr].x);
                acc[rr].y = fmaf(fmaxf(hi4[rr].y + hv.y, 0.f), aa[rr], acc[rr].y);
                acc[rr].z = fmaf(fmaxf(hi4[rr].z + hv.z, 0.f), aa[rr], acc[rr].z);
                acc[rr].w = fmaf(fmaxf(hi4[rr].w + hv.w, 0.f), aa[rr], acc[rr].w);
            }
        }
    }
    __syncthreads();       // last hjs reads done before partP alias writes

    // ---- partials, two phases (waves 0-7 then 8-15); finalize asum
    if (wv < 8) {
        float* pp = partP + wv * 1024 + rh * 4 * DD;
        #pragma unroll
        for (int rr = 0; rr < 4; ++rr)
            *(float4*)&pp[rr * DD + dq * 4] = acc[rr];
    }
    __syncthreads();
    if (tid < 8)
        asum_s[tid] = asub[tid * 4] + asub[tid * 4 + 1]
                    + asub[tid * 4 + 2] + asub[tid * 4 + 3];
    {
        float s = 0.f;
        #pragma unroll
        for (int w = 0; w < 8; ++w) s += partP[w * 1024 + tid];
        ssp[tid] = s;
    }
    __syncthreads();
    if (wv >= 8) {
        float* pp = partP + (wv - 8) * 1024 + rh * 4 * DD;
        #pragma unroll
        for (int rr = 0; rr < 4; ++rr)
            *(float4*)&pp[rr * DD + dq * 4] = acc[rr];
    }
    __syncthreads();
    {
        float s = ssp[tid];
        #pragma unroll
        for (int w = 0; w < 8; ++w) s += partP[w * 1024 + tid];
        ssp[tid] = s;
    }
    __syncthreads();

    // ---- tail: 1 col/thread (dp), 8-way k-split (kg), 16 k each (R19)
    const int dp = tid & 127;
    const int kg = tid >> 7;            // 0..7
    const int kb = kg * 16;

    // stage A: agg = ssp @ w2 (+ b2*asum at combine)
    {
        float w0[16];
        #pragma unroll
        for (int k = 0; k < 16; ++k) w0[k] = w2[(kb + k) * DD + dp];
        #pragma unroll
        for (int r = 0; r < 8; ++r) {
            float a0 = 0.f;
            #pragma unroll
            for (int q = 0; q < 4; ++q) {
                const float4 sv = *(const float4*)&ssp[r * 128 + kb + q * 4];
                a0 = fmaf(sv.x, w0[q*4+0], a0);
                a0 = fmaf(sv.y, w0[q*4+1], a0);
                a0 = fmaf(sv.z, w0[q*4+2], a0);
                a0 = fmaf(sv.w, w0[q*4+3], a0);
            }
            partT[kg * 1024 + r * 128 + dp] = a0;
        }
    }
    __syncthreads();
    {
        int r = tid >> 7, d = tid & 127;
        float s = 0.f;
        #pragma unroll
        for (int w = 0; w < 8; ++w) s += partT[w * 1024 + tid];
        aggs[tid] = s + b2[d] * asum_s[r];
    }
    __syncthreads();

    // stage B: u1 = relu(x@w3a + agg@w3b + b3)
    {
        float wa0[16], wb0[16];
        #pragma unroll
        for (int k = 0; k < 16; ++k) {
            wa0[k] = w3[(kb + k) * DD + dp];
            wb0[k] = w3[(DD + kb + k) * DD + dp];
        }
        #pragma unroll
        for (int r = 0; r < 8; ++r) {
            float a0 = 0.f;
            #pragma unroll
            for (int q = 0; q < 4; ++q) {
                const float4 xv = *(const float4*)&xs[r * 128 + kb + q * 4];
                const float4 av = *(const float4*)&aggs[r * 128 + kb + q * 4];
                a0 = fmaf(xv.x, wa0[q*4+0], a0);
                a0 = fmaf(xv.y, wa0[q*4+1], a0);
                a0 = fmaf(xv.z, wa0[q*4+2], a0);
                a0 = fmaf(xv.w, wa0[q*4+3], a0);
                a0 = fmaf(av.x, wb0[q*4+0], a0);
                a0 = fmaf(av.y, wb0[q*4+1], a0);
                a0 = fmaf(av.z, wb0[q*4+2], a0);
                a0 = fmaf(av.w, wb0[q*4+3], a0);
            }
            partT[kg * 1024 + r * 128 + dp] = a0;
        }
    }
    __syncthreads();
    {
        int d = tid & 127;
        float s = 0.f;
        #pragma unroll
        for (int w = 0; w < 8; ++w) s += partT[w * 1024 + tid];
        u1s[tid] = fmaxf(s + b3[d], 0.f);
    }
    __syncthreads();

    // stage C: upd = u1 @ w4; res = x + upd + b4
    {
        float w0[16];
        #pragma unroll
        for (int k = 0; k < 16; ++k) w0[k] = w4[(kb + k) * DD + dp];
        #pragma unroll
        for (int r = 0; r < 8; ++r) {
            float a0 = 0.f;
            #pragma unroll
            for (int q = 0; q < 4; ++q) {
                const float4 uv = *(const float4*)&u1s[r * 128 + kb + q * 4];
                a0 = fmaf(uv.x, w0[q*4+0], a0);
                a0 = fmaf(uv.y, w0[q*4+1], a0);
                a0 = fmaf(uv.z, w0[q*4+2], a0);
                a0 = fmaf(uv.w, w0[q*4+3], a0);
            }
            partT[kg * 1024 + r * 128 + dp] = a0;
        }
    }
    __syncthreads();
    {
        int d = tid & 127;
        float s = xs[tid] + b4[d];
        #pragma unroll
        for (int w = 0; w < 8; ++w) s += partT[w * 1024 + tid];
        resS[tid] = s;
    }
    __syncthreads();

    // ---- LayerNorm: waves 0..7, one row each, 2 d's per lane
    if (tid < 512) {
        const int r = tid >> 6, l = tid & 63;
        const float2 v = *(const float2*)&resS[r * 128 + l * 2];
        float s1 = v.x + v.y;
        float s2 = v.x * v.x + v.y * v.y;
        #pragma unroll
        for (int m = 32; m; m >>= 1) {
            s1 += __shfl_xor(s1, m);
            s2 += __shfl_xor(s2, m);
        }
        const float mu = s1 * (1.f / DD);
        const float rs = rsqrtf(s2 * (1.f / DD) - mu * mu + LN_EPS);
        const int d = l * 2;
        const float2 gv = *(const float2*)&g[d];
        const float2 bv = *(const float2*)&bet[d];
        float2 o;
        o.x = (v.x - mu) * rs * gv.x + bv.x;
        o.y = (v.y - mu) * rs * gv.y + bv.y;
        *(float2*)&out[((size_t)b * NN + i0 + r) * DD + d] = o;
    }
}

extern "C" void kernel_launch(void* const* d_in, const int* in_sizes, int n_in,
                              void* d_out, int out_size, void* d_ws, size_t ws_size,
                              hipStream_t stream) {
    (void)in_sizes; (void)n_in; (void)out_size; (void)ws_size;
    const float* x      = (const float*)d_in[0];
    const float* adj    = (const float*)d_in[1];
    const float* msg_w1 = (const float*)d_in[2];
    const float* msg_b1 = (const float*)d_in[3];
    const float* msg_w2 = (const float*)d_in[4];
    const float* msg_b2 = (const float*)d_in[5];
    const float* upd_w1 = (const float*)d_in[6];
    const float* upd_b1 = (const float*)d_in[7];
    const float* upd_w2 = (const float*)d_in[8];
    const float* upd_b2 = (const float*)d_in[9];
    const float* ln_g   = (const float*)d_in[10];
    const float* ln_b   = (const float*)d_in[11];
    float* out = (float*)d_out;

    const size_t BND = (size_t)BB * NN * DD;
    float* ws  = (float*)d_ws;
    float* hi  = ws;            // B*N*D
    float* hjb = ws + BND;      // B*N*D

    k_proj<<<dim3(256), dim3(1024), 0, stream>>>(x, msg_w1, msg_b1, hi, hjb);
    k_fused<<<dim3(256), dim3(1024), 0, stream>>>(adj, x, hi, hjb,
                                                  msg_w2, msg_b2,
                                                  upd_w1, upd_b1, upd_w2, upd_b2,
                                                  ln_g, ln_b, out);
}

// Round 22
// 26.120 us; speedup vs baseline: 1.0397x; 1.0397x over previous
//
#include <hip/hip_runtime.h>

#define BB 8
#define NN 256
#define DD 128
#define LN_EPS 1e-5f

// ---------------------------------------------------------------------------
// k_proj: hi = x @ w1[:D],  hjb = x @ w1[D:] + b1   (R19 verbatim)
// grid 256 blocks (8 rows) x 1024 threads (16 waves/CU = 4/SIMD).
// ---------------------------------------------------------------------------
__global__ __launch_bounds__(1024, 4) void k_proj(const float* __restrict__ x,
                                                  const float* __restrict__ w1,
                                                  const float* __restrict__ b1,
                                                  float* __restrict__ hi,
                                                  float* __restrict__ hjb) {
    __shared__ float xs[8 * DD];       // 4 KB
    __shared__ float part[16384];      // 64 KB: A @0, B @8192
    const int bid  = blockIdx.x;
    const int row0 = (bid & 7) * NN + (bid >> 3) * 8;   // XCD-affine
    const int tid  = threadIdx.x;
    xs[tid] = x[row0 * DD + tid];      // 1024 = 8*128 exactly
    __syncthreads();

    const int dp = tid & 127;
    const int kg = tid >> 7;     // 0..7
    const int kb = kg * 16;

    float aA[8] = {}, aB[8] = {};
    #pragma unroll
    for (int k4 = 0; k4 < 4; ++k4) {
        const int k0 = kb + k4 * 4;
        float wa[4], wb[4];
        #pragma unroll
        for (int q = 0; q < 4; ++q) {
            wa[q] = w1[(k0 + q) * DD + dp];
            wb[q] = w1[(DD + k0 + q) * DD + dp];
        }
        #pragma unroll
        for (int r = 0; r < 8; ++r) {
            const float4 xv = *(const float4*)&xs[r * DD + k0];  // broadcast
            aA[r] = fmaf(xv.x, wa[0], aA[r]);
            aA[r] = fmaf(xv.y, wa[1], aA[r]);
            aA[r] = fmaf(xv.z, wa[2], aA[r]);
            aA[r] = fmaf(xv.w, wa[3], aA[r]);
            aB[r] = fmaf(xv.x, wb[0], aB[r]);
            aB[r] = fmaf(xv.y, wb[1], aB[r]);
            aB[r] = fmaf(xv.z, wb[2], aB[r]);
            aB[r] = fmaf(xv.w, wb[3], aB[r]);
        }
    }
    #pragma unroll
    for (int r = 0; r < 8; ++r) {
        part[kg * 1024 + r * DD + dp]        = aA[r];
        part[8192 + kg * 1024 + r * DD + dp] = aB[r];
    }
    __syncthreads();
    {
        int r = tid >> 7, d = tid & 127;
        float sa = 0.f, sb = 0.f;
        #pragma unroll
        for (int w = 0; w < 8; ++w) {
            sa += part[w * 1024 + r * DD + d];
            sb += part[8192 + w * 1024 + r * DD + d];
        }
        hi [(row0 + r) * DD + d] = sa;
        hjb[(row0 + r) * DD + d] = sb + b1[d];
    }
}

// ---------------------------------------------------------------------------
// k_fused: R19 structure + T14 async-STAGE split in the pair loop: issue
// tile t+1's global loads BEFORE computing tile t (192 VALU/thread hides
// the ~300cy L2 latency); only the LDS store sits between barriers.
// __launch_bounds__(1024,1): grid 256 = 1 block/CU anyway; removes the
// 64-VGPR cap so the +8 prefetch registers can't trigger spill.
// smem floats: [0,8192) hjs / partP[4][1024] / partT[8][1024]
//   [8192,10240) a_t[8][256]; aliases u1s@8192, resS@9216 after pair
//   [10240,11264) xs | [11264,12288) ssp | [12288,13312) aggs
//   [13312,13320) asum_s
// ---------------------------------------------------------------------------
__global__ __launch_bounds__(1024, 1) void k_fused(const float* __restrict__ adj,
                                                   const float* __restrict__ x,
                                                   const float* __restrict__ hi,
                                                   const float* __restrict__ hjb,
                                                   const float* __restrict__ w2,
                                                   const float* __restrict__ b2,
                                                   const float* __restrict__ w3,
                                                   const float* __restrict__ b3,
                                                   const float* __restrict__ w4,
                                                   const float* __restrict__ b4,
                                                   const float* __restrict__ g,
                                                   const float* __restrict__ bet,
                                                   float* __restrict__ out) {
    __shared__ float smem[13320];
    float* const hjs    = smem;           // [64][128]
    float* const partP  = smem;           // [4][8][128] alias
    float* const partT  = smem;           // [8][8][128] alias
    float* const a_t    = smem + 8192;    // [8][256]
    float* const u1s    = smem + 8192;    // [8][128] alias (a_t dead)
    float* const resS   = smem + 9216;    // [8][128] alias
    float* const xs     = smem + 10240;   // [8][128]
    float* const ssp    = smem + 11264;   // [8][128]
    float* const aggs   = smem + 12288;   // [8][128]
    float* const asum_s = smem + 13312;   // [8]

    const int bid = blockIdx.x;
    const int b   = bid & 7;              // XCD-affine batch
    const int i0  = (bid >> 3) * 8;
    const int tid = threadIdx.x;

    // ---- stage masked adjacency + x rows
    #pragma unroll
    for (int t = 0; t < 2; ++t) {
        int idx = tid + t * 1024;           // 0..2047
        int il = idx >> 8, j = idx & 255;
        int ig = i0 + il;
        float av = adj[((size_t)b * NN + ig) * NN + j];
        a_t[il * 256 + j] = (j == ig) ? 0.f : av;
    }
    xs[tid] = x[((size_t)b * NN + i0) * DD + tid];

    // ---- prologue: prefetch tile 0 into registers
    float4 pf0, pf1;
    {
        const float4* src = (const float4*)(hjb + ((size_t)b * NN) * DD);
        pf0 = src[tid];
        pf1 = src[tid + 1024];
    }
    __syncthreads();   // a_t/xs visible; hjs region free

    // ---- asum: waves 0..7, one row each
    if (tid < 512) {
        int r = tid >> 6, l = tid & 63;
        float s = a_t[r * 256 + l] + a_t[r * 256 + l + 64]
                + a_t[r * 256 + l + 128] + a_t[r * 256 + l + 192];
        #pragma unroll
        for (int m = 32; m; m >>= 1) s += __shfl_xor(s, m);
        if (l == 0) asum_s[r] = s;
    }

    // ---- pair: 4 tiles of 64 j; 4-way j-split (jh), 16 j per thread-tile;
    // T14 split: store prefetched tile, barrier, issue next tile's loads,
    // compute (hides L2 latency), barrier.
    const int dq  = tid & 31;        // d-quad
    const int row = (tid >> 5) & 7;
    const int jh  = tid >> 8;        // 0..3
    const float4 hi4 = *(const float4*)&hi[((size_t)b * NN + i0 + row) * DD + dq * 4];
    float4 acc = {0.f, 0.f, 0.f, 0.f};

    for (int jt = 0; jt < 4; ++jt) {
        {   // store the prefetched tile
            float4* dst = (float4*)hjs;
            dst[tid]        = pf0;
            dst[tid + 1024] = pf1;
        }
        __syncthreads();   // staging visible
        if (jt < 3) {      // issue next tile's loads (hidden under compute)
            const float4* src = (const float4*)(hjb + ((size_t)b * NN + (jt + 1) * 64) * DD);
            pf0 = src[tid];
            pf1 = src[tid + 1024];
        }
        const int jb = jh * 16;
        #pragma unroll 8
        for (int jj = 0; jj < 16; ++jj) {
            const int jl = jb + jj;
            const float4 hv = *(const float4*)&hjs[jl * 128 + dq * 4];
            const float a = a_t[row * 256 + jt * 64 + jl];
            acc.x = fmaf(fmaxf(hi4.x + hv.x, 0.f), a, acc.x);
            acc.y = fmaf(fmaxf(hi4.y + hv.y, 0.f), a, acc.y);
            acc.z = fmaf(fmaxf(hi4.z + hv.z, 0.f), a, acc.z);
            acc.w = fmaf(fmaxf(hi4.w + hv.w, 0.f), a, acc.w);
        }
        __syncthreads();   // all reads of hjs done before next store
    }
    *(float4*)&partP[jh * 1024 + row * 128 + dq * 4] = acc;
    __syncthreads();
    {
        float s = partP[tid] + partP[1024 + tid] + partP[2048 + tid] + partP[3072 + tid];
        ssp[tid] = s;
    }
    __syncthreads();

    // ---- tail: 1 col/thread (dp), 8-way k-split (kg), 16 k each (R19)
    const int dp = tid & 127;
    const int kg = tid >> 7;            // 0..7
    const int kb = kg * 16;

    // stage A: agg = ssp @ w2 (+ b2*asum at combine)
    {
        float w0[16];
        #pragma unroll
        for (int k = 0; k < 16; ++k) w0[k] = w2[(kb + k) * DD + dp];
        #pragma unroll
        for (int r = 0; r < 8; ++r) {
            float a0 = 0.f;
            #pragma unroll
            for (int q = 0; q < 4; ++q) {
                const float4 sv = *(const float4*)&ssp[r * 128 + kb + q * 4];
                a0 = fmaf(sv.x, w0[q*4+0], a0);
                a0 = fmaf(sv.y, w0[q*4+1], a0);
                a0 = fmaf(sv.z, w0[q*4+2], a0);
                a0 = fmaf(sv.w, w0[q*4+3], a0);
            }
            partT[kg * 1024 + r * 128 + dp] = a0;
        }
    }
    __syncthreads();
    {
        int r = tid >> 7, d = tid & 127;
        float s = 0.f;
        #pragma unroll
        for (int w = 0; w < 8; ++w) s += partT[w * 1024 + tid];
        aggs[tid] = s + b2[d] * asum_s[r];
    }
    __syncthreads();

    // stage B: u1 = relu(x@w3a + agg@w3b + b3)
    {
        float wa0[16], wb0[16];
        #pragma unroll
        for (int k = 0; k < 16; ++k) {
            wa0[k] = w3[(kb + k) * DD + dp];
            wb0[k] = w3[(DD + kb + k) * DD + dp];
        }
        #pragma unroll
        for (int r = 0; r < 8; ++r) {
            float a0 = 0.f;
            #pragma unroll
            for (int q = 0; q < 4; ++q) {
                const float4 xv = *(const float4*)&xs[r * 128 + kb + q * 4];
                const float4 av = *(const float4*)&aggs[r * 128 + kb + q * 4];
                a0 = fmaf(xv.x, wa0[q*4+0], a0);
                a0 = fmaf(xv.y, wa0[q*4+1], a0);
                a0 = fmaf(xv.z, wa0[q*4+2], a0);
                a0 = fmaf(xv.w, wa0[q*4+3], a0);
                a0 = fmaf(av.x, wb0[q*4+0], a0);
                a0 = fmaf(av.y, wb0[q*4+1], a0);
                a0 = fmaf(av.z, wb0[q*4+2], a0);
                a0 = fmaf(av.w, wb0[q*4+3], a0);
            }
            partT[kg * 1024 + r * 128 + dp] = a0;
        }
    }
    __syncthreads();
    {
        int d = tid & 127;
        float s = 0.f;
        #pragma unroll
        for (int w = 0; w < 8; ++w) s += partT[w * 1024 + tid];
        u1s[tid] = fmaxf(s + b3[d], 0.f);
    }
    __syncthreads();

    // stage C: upd = u1 @ w4; res = x + upd + b4
    {
        float w0[16];
        #pragma unroll
        for (int k = 0; k < 16; ++k) w0[k] = w4[(kb + k) * DD + dp];
        #pragma unroll
        for (int r = 0; r < 8; ++r) {
            float a0 = 0.f;
            #pragma unroll
            for (int q = 0; q < 4; ++q) {
                const float4 uv = *(const float4*)&u1s[r * 128 + kb + q * 4];
                a0 = fmaf(uv.x, w0[q*4+0], a0);
                a0 = fmaf(uv.y, w0[q*4+1], a0);
                a0 = fmaf(uv.z, w0[q*4+2], a0);
                a0 = fmaf(uv.w, w0[q*4+3], a0);
            }
            partT[kg * 1024 + r * 128 + dp] = a0;
        }
    }
    __syncthreads();
    {
        int d = tid & 127;
        float s = xs[tid] + b4[d];
        #pragma unroll
        for (int w = 0; w < 8; ++w) s += partT[w * 1024 + tid];
        resS[tid] = s;
    }
    __syncthreads();

    // ---- LayerNorm: waves 0..7, one row each, 2 d's per lane
    if (tid < 512) {
        const int r = tid >> 6, l = tid & 63;
        const float2 v = *(const float2*)&resS[r * 128 + l * 2];
        float s1 = v.x + v.y;
        float s2 = v.x * v.x + v.y * v.y;
        #pragma unroll
        for (int m = 32; m; m >>= 1) {
            s1 += __shfl_xor(s1, m);
            s2 += __shfl_xor(s2, m);
        }
        const float mu = s1 * (1.f / DD);
        const float rs = rsqrtf(s2 * (1.f / DD) - mu * mu + LN_EPS);
        const int d = l * 2;
        const float2 gv = *(const float2*)&g[d];
        const float2 bv = *(const float2*)&bet[d];
        float2 o;
        o.x = (v.x - mu) * rs * gv.x + bv.x;
        o.y = (v.y - mu) * rs * gv.y + bv.y;
        *(float2*)&out[((size_t)b * NN + i0 + r) * DD + d] = o;
    }
}

extern "C" void kernel_launch(void* const* d_in, const int* in_sizes, int n_in,
                              void* d_out, int out_size, void* d_ws, size_t ws_size,
                              hipStream_t stream) {
    (void)in_sizes; (void)n_in; (void)out_size; (void)ws_size;
    const float* x      = (const float*)d_in[0];
    const float* adj    = (const float*)d_in[1];
    const float* msg_w1 = (const float*)d_in[2];
    const float* msg_b1 = (const float*)d_in[3];
    const float* msg_w2 = (const float*)d_in[4];
    const float* msg_b2 = (const float*)d_in[5];
    const float* upd_w1 = (const float*)d_in[6];
    const float* upd_b1 = (const float*)d_in[7];
    const float* upd_w2 = (const float*)d_in[8];
    const float* upd_b2 = (const float*)d_in[9];
    const float* ln_g   = (const float*)d_in[10];
    const float* ln_b   = (const float*)d_in[11];
    float* out = (float*)d_out;

    const size_t BND = (size_t)BB * NN * DD;
    float* ws  = (float*)d_ws;
    float* hi  = ws;            // B*N*D
    float* hjb = ws + BND;      // B*N*D

    k_proj<<<dim3(256), dim3(1024), 0, stream>>>(x, msg_w1, msg_b1, hi, hjb);
    k_fused<<<dim3(256), dim3(1024), 0, stream>>>(adj, x, hi, hjb,
                                                  msg_w2, msg_b2,
                                                  upd_w1, upd_b1, upd_w2, upd_b2,
                                                  ln_g, ln_b, out);
}

// Round 23
// 24.994 us; speedup vs baseline: 1.0865x; 1.0451x over previous
//
#include <hip/hip_runtime.h>

#define BB 8
#define NN 256
#define DD 128
#define LN_EPS 1e-5f

// ---------------------------------------------------------------------------
// k_proj: hi = x @ w1[:D],  hjb = x @ w1[D:] + b1
// grid 256 blocks (8 rows) x 1024 threads (16 waves/CU = 4/SIMD).
// dp = tid&127 (output col), kg = tid>>7 (8-way k-split, 16 k each).
// XCD-affinity: batch = bid & 7.
// ---------------------------------------------------------------------------
__global__ __launch_bounds__(1024, 4) void k_proj(const float* __restrict__ x,
                                                  const float* __restrict__ w1,
                                                  const float* __restrict__ b1,
                                                  float* __restrict__ hi,
                                                  float* __restrict__ hjb) {
    __shared__ float xs[8 * DD];       // 4 KB
    __shared__ float part[16384];      // 64 KB: A @0, B @8192
    const int bid  = blockIdx.x;
    const int row0 = (bid & 7) * NN + (bid >> 3) * 8;   // XCD-affine
    const int tid  = threadIdx.x;
    xs[tid] = x[row0 * DD + tid];      // 1024 = 8*128 exactly
    __syncthreads();

    const int dp = tid & 127;
    const int kg = tid >> 7;     // 0..7
    const int kb = kg * 16;

    float aA[8] = {}, aB[8] = {};
    #pragma unroll
    for (int k4 = 0; k4 < 4; ++k4) {
        const int k0 = kb + k4 * 4;
        float wa[4], wb[4];
        #pragma unroll
        for (int q = 0; q < 4; ++q) {
            wa[q] = w1[(k0 + q) * DD + dp];
            wb[q] = w1[(DD + k0 + q) * DD + dp];
        }
        #pragma unroll
        for (int r = 0; r < 8; ++r) {
            const float4 xv = *(const float4*)&xs[r * DD + k0];  // broadcast
            aA[r] = fmaf(xv.x, wa[0], aA[r]);
            aA[r] = fmaf(xv.y, wa[1], aA[r]);
            aA[r] = fmaf(xv.z, wa[2], aA[r]);
            aA[r] = fmaf(xv.w, wa[3], aA[r]);
            aB[r] = fmaf(xv.x, wb[0], aB[r]);
            aB[r] = fmaf(xv.y, wb[1], aB[r]);
            aB[r] = fmaf(xv.z, wb[2], aB[r]);
            aB[r] = fmaf(xv.w, wb[3], aB[r]);
        }
    }
    #pragma unroll
    for (int r = 0; r < 8; ++r) {
        part[kg * 1024 + r * DD + dp]        = aA[r];
        part[8192 + kg * 1024 + r * DD + dp] = aB[r];
    }
    __syncthreads();
    {
        int r = tid >> 7, d = tid & 127;
        float sa = 0.f, sb = 0.f;
        #pragma unroll
        for (int w = 0; w < 8; ++w) {
            sa += part[w * 1024 + r * DD + d];
            sb += part[8192 + w * 1024 + r * DD + d];
        }
        hi [(row0 + r) * DD + d] = sa;
        hjb[(row0 + r) * DD + d] = sb + b1[d];
    }
}

// ---------------------------------------------------------------------------
// k_fused: champion work decomposition (256 blocks, 8 rows, 64-j LDS tiles)
// at 1024 threads (16 waves/CU = 4/SIMD). XCD-affine (b = bid & 7).
// Pair: dq = tid&31 (4 d), row = (tid>>5)&7, jh = tid>>8 (4-way j-split,
// 16 j each); partials [4][8][128] alias dead hjs. Tail: 1 col/thread
// (dp = tid&127), kg = tid>>7 (8-way k-split); partT[8][8][128] alias.
// smem floats: [0,8192) hjs / partP(4K) / partT(8K)
//   [8192,10240) a_t[8][256]; aliases u1s@8192, resS@9216 after pair
//   [10240,11264) xs | [11264,12288) ssp | [12288,13312) aggs
//   [13312,13320) asum_s
// ---------------------------------------------------------------------------
__global__ __launch_bounds__(1024, 4) void k_fused(const float* __restrict__ adj,
                                                   const float* __restrict__ x,
                                                   const float* __restrict__ hi,
                                                   const float* __restrict__ hjb,
                                                   const float* __restrict__ w2,
                                                   const float* __restrict__ b2,
                                                   const float* __restrict__ w3,
                                                   const float* __restrict__ b3,
                                                   const float* __restrict__ w4,
                                                   const float* __restrict__ b4,
                                                   const float* __restrict__ g,
                                                   const float* __restrict__ bet,
                                                   float* __restrict__ out) {
    __shared__ float smem[13320];
    float* const hjs    = smem;           // [64][128]
    float* const partP  = smem;           // [4][8][128] alias
    float* const partT  = smem;           // [8][8][128] alias
    float* const a_t    = smem + 8192;    // [8][256]
    float* const u1s    = smem + 8192;    // [8][128] alias (a_t dead)
    float* const resS   = smem + 9216;    // [8][128] alias
    float* const xs     = smem + 10240;   // [8][128]
    float* const ssp    = smem + 11264;   // [8][128]
    float* const aggs   = smem + 12288;   // [8][128]
    float* const asum_s = smem + 13312;   // [8]

    const int bid = blockIdx.x;
    const int b   = bid & 7;              // XCD-affine batch
    const int i0  = (bid >> 3) * 8;
    const int tid = threadIdx.x;

    // ---- stage masked adjacency + x rows
    #pragma unroll
    for (int t = 0; t < 2; ++t) {
        int idx = tid + t * 1024;           // 0..2047
        int il = idx >> 8, j = idx & 255;
        int ig = i0 + il;
        float av = adj[((size_t)b * NN + ig) * NN + j];
        a_t[il * 256 + j] = (j == ig) ? 0.f : av;
    }
    xs[tid] = x[((size_t)b * NN + i0) * DD + tid];
    __syncthreads();

    // ---- asum: waves 0..7, one row each
    if (tid < 512) {
        int r = tid >> 6, l = tid & 63;
        float s = a_t[r * 256 + l] + a_t[r * 256 + l + 64]
                + a_t[r * 256 + l + 128] + a_t[r * 256 + l + 192];
        #pragma unroll
        for (int m = 32; m; m >>= 1) s += __shfl_xor(s, m);
        if (l == 0) asum_s[r] = s;
    }

    // ---- pair: 4 tiles of 64 j; 4-way j-split (jh), 16 j per thread-tile
    const int dq  = tid & 31;        // d-quad
    const int row = (tid >> 5) & 7;
    const int jh  = tid >> 8;        // 0..3
    const float4 hi4 = *(const float4*)&hi[((size_t)b * NN + i0 + row) * DD + dq * 4];
    float4 acc = {0.f, 0.f, 0.f, 0.f};

    for (int jt = 0; jt < 4; ++jt) {
        __syncthreads();   // prev tile reads done (tt=0: staging visible)
        const float4* src = (const float4*)(hjb + ((size_t)b * NN + jt * 64) * DD);
        float4* dst = (float4*)hjs;
        #pragma unroll
        for (int t = 0; t < 2; ++t) dst[tid + t * 1024] = src[tid + t * 1024];
        __syncthreads();
        const int jb = jh * 16;
        #pragma unroll 8
        for (int jj = 0; jj < 16; ++jj) {
            const int jl = jb + jj;
            const float4 hv = *(const float4*)&hjs[jl * 128 + dq * 4];
            const float a = a_t[row * 256 + jt * 64 + jl];
            acc.x = fmaf(fmaxf(hi4.x + hv.x, 0.f), a, acc.x);
            acc.y = fmaf(fmaxf(hi4.y + hv.y, 0.f), a, acc.y);
            acc.z = fmaf(fmaxf(hi4.z + hv.z, 0.f), a, acc.z);
            acc.w = fmaf(fmaxf(hi4.w + hv.w, 0.f), a, acc.w);
        }
    }
    __syncthreads();       // last hjs reads done before partP alias writes
    *(float4*)&partP[jh * 1024 + row * 128 + dq * 4] = acc;
    __syncthreads();
    {
        float s = partP[tid] + partP[1024 + tid] + partP[2048 + tid] + partP[3072 + tid];
        ssp[tid] = s;
    }
    __syncthreads();

    // ---- tail: 1 col/thread (dp), 8-way k-split (kg), 16 k each
    const int dp = tid & 127;
    const int kg = tid >> 7;            // 0..7
    const int kb = kg * 16;

    // stage A: agg = ssp @ w2 (+ b2*asum at combine)
    {
        float w0[16];
        #pragma unroll
        for (int k = 0; k < 16; ++k) w0[k] = w2[(kb + k) * DD + dp];
        #pragma unroll
        for (int r = 0; r < 8; ++r) {
            float a0 = 0.f;
            #pragma unroll
            for (int q = 0; q < 4; ++q) {
                const float4 sv = *(const float4*)&ssp[r * 128 + kb + q * 4];
                a0 = fmaf(sv.x, w0[q*4+0], a0);
                a0 = fmaf(sv.y, w0[q*4+1], a0);
                a0 = fmaf(sv.z, w0[q*4+2], a0);
                a0 = fmaf(sv.w, w0[q*4+3], a0);
            }
            partT[kg * 1024 + r * 128 + dp] = a0;
        }
    }
    __syncthreads();
    {
        int r = tid >> 7, d = tid & 127;
        float s = 0.f;
        #pragma unroll
        for (int w = 0; w < 8; ++w) s += partT[w * 1024 + tid];
        aggs[tid] = s + b2[d] * asum_s[r];
    }
    __syncthreads();

    // stage B: u1 = relu(x@w3a + agg@w3b + b3)
    {
        float wa0[16], wb0[16];
        #pragma unroll
        for (int k = 0; k < 16; ++k) {
            wa0[k] = w3[(kb + k) * DD + dp];
            wb0[k] = w3[(DD + kb + k) * DD + dp];
        }
        #pragma unroll
        for (int r = 0; r < 8; ++r) {
            float a0 = 0.f;
            #pragma unroll
            for (int q = 0; q < 4; ++q) {
                const float4 xv = *(const float4*)&xs[r * 128 + kb + q * 4];
                const float4 av = *(const float4*)&aggs[r * 128 + kb + q * 4];
                a0 = fmaf(xv.x, wa0[q*4+0], a0);
                a0 = fmaf(xv.y, wa0[q*4+1], a0);
                a0 = fmaf(xv.z, wa0[q*4+2], a0);
                a0 = fmaf(xv.w, wa0[q*4+3], a0);
                a0 = fmaf(av.x, wb0[q*4+0], a0);
                a0 = fmaf(av.y, wb0[q*4+1], a0);
                a0 = fmaf(av.z, wb0[q*4+2], a0);
                a0 = fmaf(av.w, wb0[q*4+3], a0);
            }
            partT[kg * 1024 + r * 128 + dp] = a0;
        }
    }
    __syncthreads();
    {
        int d = tid & 127;
        float s = 0.f;
        #pragma unroll
        for (int w = 0; w < 8; ++w) s += partT[w * 1024 + tid];
        u1s[tid] = fmaxf(s + b3[d], 0.f);
    }
    __syncthreads();

    // stage C: upd = u1 @ w4; res = x + upd + b4
    {
        float w0[16];
        #pragma unroll
        for (int k = 0; k < 16; ++k) w0[k] = w4[(kb + k) * DD + dp];
        #pragma unroll
        for (int r = 0; r < 8; ++r) {
            float a0 = 0.f;
            #pragma unroll
            for (int q = 0; q < 4; ++q) {
                const float4 uv = *(const float4*)&u1s[r * 128 + kb + q * 4];
                a0 = fmaf(uv.x, w0[q*4+0], a0);
                a0 = fmaf(uv.y, w0[q*4+1], a0);
                a0 = fmaf(uv.z, w0[q*4+2], a0);
                a0 = fmaf(uv.w, w0[q*4+3], a0);
            }
            partT[kg * 1024 + r * 128 + dp] = a0;
        }
    }
    __syncthreads();
    {
        int d = tid & 127;
        float s = xs[tid] + b4[d];
        #pragma unroll
        for (int w = 0; w < 8; ++w) s += partT[w * 1024 + tid];
        resS[tid] = s;
    }
    __syncthreads();

    // ---- LayerNorm: waves 0..7, one row each, 2 d's per lane
    if (tid < 512) {
        const int r = tid >> 6, l = tid & 63;
        const float2 v = *(const float2*)&resS[r * 128 + l * 2];
        float s1 = v.x + v.y;
        float s2 = v.x * v.x + v.y * v.y;
        #pragma unroll
        for (int m = 32; m; m >>= 1) {
            s1 += __shfl_xor(s1, m);
            s2 += __shfl_xor(s2, m);
        }
        const float mu = s1 * (1.f / DD);
        const float rs = rsqrtf(s2 * (1.f / DD) - mu * mu + LN_EPS);
        const int d = l * 2;
        const float2 gv = *(const float2*)&g[d];
        const float2 bv = *(const float2*)&bet[d];
        float2 o;
        o.x = (v.x - mu) * rs * gv.x + bv.x;
        o.y = (v.y - mu) * rs * gv.y + bv.y;
        *(float2*)&out[((size_t)b * NN + i0 + r) * DD + d] = o;
    }
}

extern "C" void kernel_launch(void* const* d_in, const int* in_sizes, int n_in,
                              void* d_out, int out_size, void* d_ws, size_t ws_size,
                              hipStream_t stream) {
    (void)in_sizes; (void)n_in; (void)out_size; (void)ws_size;
    const float* x      = (const float*)d_in[0];
    const float* adj    = (const float*)d_in[1];
    const float* msg_w1 = (const float*)d_in[2];
    const float* msg_b1 = (const float*)d_in[3];
    const float* msg_w2 = (const float*)d_in[4];
    const float* msg_b2 = (const float*)d_in[5];
    const float* upd_w1 = (const float*)d_in[6];
    const float* upd_b1 = (const float*)d_in[7];
    const float* upd_w2 = (const float*)d_in[8];
    const float* upd_b2 = (const float*)d_in[9];
    const float* ln_g   = (const float*)d_in[10];
    const float* ln_b   = (const float*)d_in[11];
    float* out = (float*)d_out;

    const size_t BND = (size_t)BB * NN * DD;
    float* ws  = (float*)d_ws;
    float* hi  = ws;            // B*N*D
    float* hjb = ws + BND;      // B*N*D

    k_proj<<<dim3(256), dim3(1024), 0, stream>>>(x, msg_w1, msg_b1, hi, hjb);
    k_fused<<<dim3(256), dim3(1024), 0, stream>>>(adj, x, hi, hjb,
                                                  msg_w2, msg_b2,
                                                  upd_w1, upd_b1, upd_w2, upd_b2,
                                                  ln_g, ln_b, out);
}

// Round 24
// 24.716 us; speedup vs baseline: 1.0987x; 1.0113x over previous
//
#include <hip/hip_runtime.h>

#define BB 8
#define NN 256
#define DD 128
#define LN_EPS 1e-5f

// ---------------------------------------------------------------------------
// k_proj: hi = x @ w1[:D],  hjb = x @ w1[D:] + b1   (R19 verbatim)
// grid 256 blocks (8 rows) x 1024 threads (16 waves/CU = 4/SIMD).
// ---------------------------------------------------------------------------
__global__ __launch_bounds__(1024, 4) void k_proj(const float* __restrict__ x,
                                                  const float* __restrict__ w1,
                                                  const float* __restrict__ b1,
                                                  float* __restrict__ hi,
                                                  float* __restrict__ hjb) {
    __shared__ float xs[8 * DD];       // 4 KB
    __shared__ float part[16384];      // 64 KB: A @0, B @8192
    const int bid  = blockIdx.x;
    const int row0 = (bid & 7) * NN + (bid >> 3) * 8;   // XCD-affine
    const int tid  = threadIdx.x;
    xs[tid] = x[row0 * DD + tid];      // 1024 = 8*128 exactly
    __syncthreads();

    const int dp = tid & 127;
    const int kg = tid >> 7;     // 0..7
    const int kb = kg * 16;

    float aA[8] = {}, aB[8] = {};
    #pragma unroll
    for (int k4 = 0; k4 < 4; ++k4) {
        const int k0 = kb + k4 * 4;
        float wa[4], wb[4];
        #pragma unroll
        for (int q = 0; q < 4; ++q) {
            wa[q] = w1[(k0 + q) * DD + dp];
            wb[q] = w1[(DD + k0 + q) * DD + dp];
        }
        #pragma unroll
        for (int r = 0; r < 8; ++r) {
            const float4 xv = *(const float4*)&xs[r * DD + k0];  // broadcast
            aA[r] = fmaf(xv.x, wa[0], aA[r]);
            aA[r] = fmaf(xv.y, wa[1], aA[r]);
            aA[r] = fmaf(xv.z, wa[2], aA[r]);
            aA[r] = fmaf(xv.w, wa[3], aA[r]);
            aB[r] = fmaf(xv.x, wb[0], aB[r]);
            aB[r] = fmaf(xv.y, wb[1], aB[r]);
            aB[r] = fmaf(xv.z, wb[2], aB[r]);
            aB[r] = fmaf(xv.w, wb[3], aB[r]);
        }
    }
    #pragma unroll
    for (int r = 0; r < 8; ++r) {
        part[kg * 1024 + r * DD + dp]        = aA[r];
        part[8192 + kg * 1024 + r * DD + dp] = aB[r];
    }
    __syncthreads();
    {
        int r = tid >> 7, d = tid & 127;
        float sa = 0.f, sb = 0.f;
        #pragma unroll
        for (int w = 0; w < 8; ++w) {
            sa += part[w * 1024 + r * DD + d];
            sb += part[8192 + w * 1024 + r * DD + d];
        }
        hi [(row0 + r) * DD + d] = sa;
        hjb[(row0 + r) * DD + d] = sb + b1[d];
    }
}

// ---------------------------------------------------------------------------
// k_fused: R19 structure with the pair phase's 4-tile staging replaced by a
// ONE-SHOT full-batch hjb stage into 128 KB of dynamic LDS: zero in-loop
// barriers, one pipelined 8xfloat4 staging burst per thread.
// Dynamic LDS layout (floats), total 37896 (~148 KB -> 1 block/CU):
//   [0,32768)     hall[256][128]  (aliased by partP[4][1024]/partT[8][1024]
//                                  after the pair phase)
//   [32768,34816) a_t[8][256]     (aliased by u1s@32768, resS@33792 in tail)
//   [34816,35840) xs[8][128]
//   [35840,36864) ssp[8][128]
//   [36864,37888) aggs[8][128]
//   [37888,37896) asum_s[8]
// Mappings identical to R19. XCD-affine (b = bid & 7).
// ---------------------------------------------------------------------------
__global__ __launch_bounds__(1024, 4) void k_fused(const float* __restrict__ adj,
                                                   const float* __restrict__ x,
                                                   const float* __restrict__ hi,
                                                   const float* __restrict__ hjb,
                                                   const float* __restrict__ w2,
                                                   const float* __restrict__ b2,
                                                   const float* __restrict__ w3,
                                                   const float* __restrict__ b3,
                                                   const float* __restrict__ w4,
                                                   const float* __restrict__ b4,
                                                   const float* __restrict__ g,
                                                   const float* __restrict__ bet,
                                                   float* __restrict__ out) {
    extern __shared__ float smem[];
    float* const hall   = smem;            // [256][128]
    float* const partP  = smem;            // [4][1024] alias (pair done)
    float* const partT  = smem;            // [8][1024] alias
    float* const a_t    = smem + 32768;    // [8][256]
    float* const u1s    = smem + 32768;    // [8][128] alias (a_t dead)
    float* const resS   = smem + 33792;    // [8][128] alias
    float* const xs     = smem + 34816;    // [8][128]
    float* const ssp    = smem + 35840;    // [8][128]
    float* const aggs   = smem + 36864;    // [8][128]
    float* const asum_s = smem + 37888;    // [8]

    const int bid = blockIdx.x;
    const int b   = bid & 7;               // XCD-affine batch
    const int i0  = (bid >> 3) * 8;
    const int tid = threadIdx.x;

    // ---- stage FULL batch hjb (128 KB), masked adjacency, x rows
    {
        const float4* src = (const float4*)(hjb + ((size_t)b * NN) * DD);
        float4* dst = (float4*)hall;
        #pragma unroll
        for (int t = 0; t < 8; ++t) dst[tid + t * 1024] = src[tid + t * 1024];
    }
    #pragma unroll
    for (int t = 0; t < 2; ++t) {
        int idx = tid + t * 1024;           // 0..2047
        int il = idx >> 8, j = idx & 255;
        int ig = i0 + il;
        float av = adj[((size_t)b * NN + ig) * NN + j];
        a_t[il * 256 + j] = (j == ig) ? 0.f : av;
    }
    xs[tid] = x[((size_t)b * NN + i0) * DD + tid];
    __syncthreads();

    // ---- asum: waves 0..7, one row each
    if (tid < 512) {
        int r = tid >> 6, l = tid & 63;
        float s = a_t[r * 256 + l] + a_t[r * 256 + l + 64]
                + a_t[r * 256 + l + 128] + a_t[r * 256 + l + 192];
        #pragma unroll
        for (int m = 32; m; m >>= 1) s += __shfl_xor(s, m);
        if (l == 0) asum_s[r] = s;
    }

    // ---- pair: 64 j per thread, NO barriers in the loop
    const int dq  = tid & 31;        // d-quad
    const int row = (tid >> 5) & 7;
    const int jh  = tid >> 8;        // 0..3 (j-quarter)
    const float4 hi4 = *(const float4*)&hi[((size_t)b * NN + i0 + row) * DD + dq * 4];
    float4 acc = {0.f, 0.f, 0.f, 0.f};
    {
        const int j0 = jh * 64;
        #pragma unroll 8
        for (int jj = 0; jj < 64; ++jj) {
            const int j = j0 + jj;
            const float4 hv = *(const float4*)&hall[j * 128 + dq * 4];
            const float a = a_t[row * 256 + j];
            acc.x = fmaf(fmaxf(hi4.x + hv.x, 0.f), a, acc.x);
            acc.y = fmaf(fmaxf(hi4.y + hv.y, 0.f), a, acc.y);
            acc.z = fmaf(fmaxf(hi4.z + hv.z, 0.f), a, acc.z);
            acc.w = fmaf(fmaxf(hi4.w + hv.w, 0.f), a, acc.w);
        }
    }
    __syncthreads();       // all hall reads done before partP alias writes
    *(float4*)&partP[jh * 1024 + row * 128 + dq * 4] = acc;
    __syncthreads();
    {
        float s = partP[tid] + partP[1024 + tid] + partP[2048 + tid] + partP[3072 + tid];
        ssp[tid] = s;
    }
    __syncthreads();

    // ---- tail: 1 col/thread (dp), 8-way k-split (kg), 16 k each (R19)
    const int dp = tid & 127;
    const int kg = tid >> 7;            // 0..7
    const int kb = kg * 16;

    // stage A: agg = ssp @ w2 (+ b2*asum at combine)
    {
        float w0[16];
        #pragma unroll
        for (int k = 0; k < 16; ++k) w0[k] = w2[(kb + k) * DD + dp];
        #pragma unroll
        for (int r = 0; r < 8; ++r) {
            float a0 = 0.f;
            #pragma unroll
            for (int q = 0; q < 4; ++q) {
                const float4 sv = *(const float4*)&ssp[r * 128 + kb + q * 4];
                a0 = fmaf(sv.x, w0[q*4+0], a0);
                a0 = fmaf(sv.y, w0[q*4+1], a0);
                a0 = fmaf(sv.z, w0[q*4+2], a0);
                a0 = fmaf(sv.w, w0[q*4+3], a0);
            }
            partT[kg * 1024 + r * 128 + dp] = a0;
        }
    }
    __syncthreads();
    {
        int r = tid >> 7, d = tid & 127;
        float s = 0.f;
        #pragma unroll
        for (int w = 0; w < 8; ++w) s += partT[w * 1024 + tid];
        aggs[tid] = s + b2[d] * asum_s[r];
    }
    __syncthreads();

    // stage B: u1 = relu(x@w3a + agg@w3b + b3)
    {
        float wa0[16], wb0[16];
        #pragma unroll
        for (int k = 0; k < 16; ++k) {
            wa0[k] = w3[(kb + k) * DD + dp];
            wb0[k] = w3[(DD + kb + k) * DD + dp];
        }
        #pragma unroll
        for (int r = 0; r < 8; ++r) {
            float a0 = 0.f;
            #pragma unroll
            for (int q = 0; q < 4; ++q) {
                const float4 xv = *(const float4*)&xs[r * 128 + kb + q * 4];
                const float4 av = *(const float4*)&aggs[r * 128 + kb + q * 4];
                a0 = fmaf(xv.x, wa0[q*4+0], a0);
                a0 = fmaf(xv.y, wa0[q*4+1], a0);
                a0 = fmaf(xv.z, wa0[q*4+2], a0);
                a0 = fmaf(xv.w, wa0[q*4+3], a0);
                a0 = fmaf(av.x, wb0[q*4+0], a0);
                a0 = fmaf(av.y, wb0[q*4+1], a0);
                a0 = fmaf(av.z, wb0[q*4+2], a0);
                a0 = fmaf(av.w, wb0[q*4+3], a0);
            }
            partT[kg * 1024 + r * 128 + dp] = a0;
        }
    }
    __syncthreads();
    {
        int d = tid & 127;
        float s = 0.f;
        #pragma unroll
        for (int w = 0; w < 8; ++w) s += partT[w * 1024 + tid];
        u1s[tid] = fmaxf(s + b3[d], 0.f);
    }
    __syncthreads();

    // stage C: upd = u1 @ w4; res = x + upd + b4
    {
        float w0[16];
        #pragma unroll
        for (int k = 0; k < 16; ++k) w0[k] = w4[(kb + k) * DD + dp];
        #pragma unroll
        for (int r = 0; r < 8; ++r) {
            float a0 = 0.f;
            #pragma unroll
            for (int q = 0; q < 4; ++q) {
                const float4 uv = *(const float4*)&u1s[r * 128 + kb + q * 4];
                a0 = fmaf(uv.x, w0[q*4+0], a0);
                a0 = fmaf(uv.y, w0[q*4+1], a0);
                a0 = fmaf(uv.z, w0[q*4+2], a0);
                a0 = fmaf(uv.w, w0[q*4+3], a0);
            }
            partT[kg * 1024 + r * 128 + dp] = a0;
        }
    }
    __syncthreads();
    {
        int d = tid & 127;
        float s = xs[tid] + b4[d];
        #pragma unroll
        for (int w = 0; w < 8; ++w) s += partT[w * 1024 + tid];
        resS[tid] = s;
    }
    __syncthreads();

    // ---- LayerNorm: waves 0..7, one row each, 2 d's per lane
    if (tid < 512) {
        const int r = tid >> 6, l = tid & 63;
        const float2 v = *(const float2*)&resS[r * 128 + l * 2];
        float s1 = v.x + v.y;
        float s2 = v.x * v.x + v.y * v.y;
        #pragma unroll
        for (int m = 32; m; m >>= 1) {
            s1 += __shfl_xor(s1, m);
            s2 += __shfl_xor(s2, m);
        }
        const float mu = s1 * (1.f / DD);
        const float rs = rsqrtf(s2 * (1.f / DD) - mu * mu + LN_EPS);
        const int d = l * 2;
        const float2 gv = *(const float2*)&g[d];
        const float2 bv = *(const float2*)&bet[d];
        float2 o;
        o.x = (v.x - mu) * rs * gv.x + bv.x;
        o.y = (v.y - mu) * rs * gv.y + bv.y;
        *(float2*)&out[((size_t)b * NN + i0 + r) * DD + d] = o;
    }
}

extern "C" void kernel_launch(void* const* d_in, const int* in_sizes, int n_in,
                              void* d_out, int out_size, void* d_ws, size_t ws_size,
                              hipStream_t stream) {
    (void)in_sizes; (void)n_in; (void)out_size; (void)ws_size;
    const float* x      = (const float*)d_in[0];
    const float* adj    = (const float*)d_in[1];
    const float* msg_w1 = (const float*)d_in[2];
    const float* msg_b1 = (const float*)d_in[3];
    const float* msg_w2 = (const float*)d_in[4];
    const float* msg_b2 = (const float*)d_in[5];
    const float* upd_w1 = (const float*)d_in[6];
    const float* upd_b1 = (const float*)d_in[7];
    const float* upd_w2 = (const float*)d_in[8];
    const float* upd_b2 = (const float*)d_in[9];
    const float* ln_g   = (const float*)d_in[10];
    const float* ln_b   = (const float*)d_in[11];
    float* out = (float*)d_out;

    const size_t BND = (size_t)BB * NN * DD;
    float* ws  = (float*)d_ws;
    float* hi  = ws;            // B*N*D
    float* hjb = ws + BND;      // B*N*D

    const size_t dyn_lds = 37896 * sizeof(float);   // ~148 KB (<= 160 KB/CU)
    // Opt-in for >64 KB dynamic LDS. Host-side, idempotent, not a stream op
    // (graph-capture-safe).
    hipFuncSetAttribute((const void*)k_fused,
                        hipFuncAttributeMaxDynamicSharedMemorySize,
                        (int)dyn_lds);

    k_proj<<<dim3(256), dim3(1024), 0, stream>>>(x, msg_w1, msg_b1, hi, hjb);
    k_fused<<<dim3(256), dim3(1024), dyn_lds, stream>>>(adj, x, hi, hjb,
                                                        msg_w2, msg_b2,
                                                        upd_w1, upd_b1,
                                                        upd_w2, upd_b2,
                                                        ln_g, ln_b, out);
}

// Round 25
// 24.672 us; speedup vs baseline: 1.1007x; 1.0018x over previous
//
#include <hip/hip_runtime.h>

#define BB 8
#define NN 256
#define DD 128
#define LN_EPS 1e-5f

// ---------------------------------------------------------------------------
// k_proj: hi = x @ w1[:D],  hjb = x @ w1[D:] + b1
// grid 512 blocks (4 rows each) x 512 threads -> 2 blocks/CU: one block's
// weight-load latency hides under the other's FMA (R24's proj ran 1 block/CU
// with nothing to overlap). Per-block weight stream unchanged (all of w1).
// dp = tid&127 (output col), kg = tid>>7 (4-way k-split, 32 k each).
// XCD-affinity: batch = bid & 7.
// ---------------------------------------------------------------------------
__global__ __launch_bounds__(512, 2) void k_proj(const float* __restrict__ x,
                                                 const float* __restrict__ w1,
                                                 const float* __restrict__ b1,
                                                 float* __restrict__ hi,
                                                 float* __restrict__ hjb) {
    __shared__ float xs[4 * DD];       // 2 KB
    __shared__ float part[8192];       // 32 KB: A @0, B @4096
    const int bid  = blockIdx.x;
    const int row0 = (bid & 7) * NN + (bid >> 3) * 4;   // XCD-affine, 4 rows
    const int tid  = threadIdx.x;
    xs[tid] = x[row0 * DD + tid];      // 512 = 4*128 exactly
    __syncthreads();

    const int dp = tid & 127;
    const int kg = tid >> 7;     // 0..3
    const int kb = kg * 32;

    float aA[4] = {}, aB[4] = {};
    #pragma unroll
    for (int k4 = 0; k4 < 8; ++k4) {
        const int k0 = kb + k4 * 4;
        float wa[4], wb[4];
        #pragma unroll
        for (int q = 0; q < 4; ++q) {
            wa[q] = w1[(k0 + q) * DD + dp];
            wb[q] = w1[(DD + k0 + q) * DD + dp];
        }
        #pragma unroll
        for (int r = 0; r < 4; ++r) {
            const float4 xv = *(const float4*)&xs[r * DD + k0];  // broadcast
            aA[r] = fmaf(xv.x, wa[0], aA[r]);
            aA[r] = fmaf(xv.y, wa[1], aA[r]);
            aA[r] = fmaf(xv.z, wa[2], aA[r]);
            aA[r] = fmaf(xv.w, wa[3], aA[r]);
            aB[r] = fmaf(xv.x, wb[0], aB[r]);
            aB[r] = fmaf(xv.y, wb[1], aB[r]);
            aB[r] = fmaf(xv.z, wb[2], aB[r]);
            aB[r] = fmaf(xv.w, wb[3], aB[r]);
        }
    }
    #pragma unroll
    for (int r = 0; r < 4; ++r) {
        part[kg * 512 + r * DD + dp]        = aA[r];
        part[4096 + kg * 512 + r * DD + dp] = aB[r];
    }
    __syncthreads();
    {
        int r = tid >> 7, d = tid & 127;
        float sa = 0.f, sb = 0.f;
        #pragma unroll
        for (int w = 0; w < 4; ++w) {
            sa += part[w * 512 + r * DD + d];
            sb += part[4096 + w * 512 + r * DD + d];
        }
        hi [(row0 + r) * DD + d] = sa;
        hjb[(row0 + r) * DD + d] = sb + b1[d];
    }
}

// ---------------------------------------------------------------------------
// k_fused: R24 verbatim (champion). One-shot full-batch hjb stage into
// 128 KB dynamic LDS; zero in-loop barriers in the pair phase.
// Dynamic LDS layout (floats), total 37896 (~148 KB -> 1 block/CU):
//   [0,32768)     hall[256][128]  (aliased by partP[4][1024]/partT[8][1024])
//   [32768,34816) a_t[8][256]     (aliased by u1s@32768, resS@33792 in tail)
//   [34816,35840) xs | [35840,36864) ssp | [36864,37888) aggs
//   [37888,37896) asum_s
// ---------------------------------------------------------------------------
__global__ __launch_bounds__(1024, 4) void k_fused(const float* __restrict__ adj,
                                                   const float* __restrict__ x,
                                                   const float* __restrict__ hi,
                                                   const float* __restrict__ hjb,
                                                   const float* __restrict__ w2,
                                                   const float* __restrict__ b2,
                                                   const float* __restrict__ w3,
                                                   const float* __restrict__ b3,
                                                   const float* __restrict__ w4,
                                                   const float* __restrict__ b4,
                                                   const float* __restrict__ g,
                                                   const float* __restrict__ bet,
                                                   float* __restrict__ out) {
    extern __shared__ float smem[];
    float* const hall   = smem;            // [256][128]
    float* const partP  = smem;            // [4][1024] alias (pair done)
    float* const partT  = smem;            // [8][1024] alias
    float* const a_t    = smem + 32768;    // [8][256]
    float* const u1s    = smem + 32768;    // [8][128] alias (a_t dead)
    float* const resS   = smem + 33792;    // [8][128] alias
    float* const xs     = smem + 34816;    // [8][128]
    float* const ssp    = smem + 35840;    // [8][128]
    float* const aggs   = smem + 36864;    // [8][128]
    float* const asum_s = smem + 37888;    // [8]

    const int bid = blockIdx.x;
    const int b   = bid & 7;               // XCD-affine batch
    const int i0  = (bid >> 3) * 8;
    const int tid = threadIdx.x;

    // ---- stage FULL batch hjb (128 KB), masked adjacency, x rows
    {
        const float4* src = (const float4*)(hjb + ((size_t)b * NN) * DD);
        float4* dst = (float4*)hall;
        #pragma unroll
        for (int t = 0; t < 8; ++t) dst[tid + t * 1024] = src[tid + t * 1024];
    }
    #pragma unroll
    for (int t = 0; t < 2; ++t) {
        int idx = tid + t * 1024;           // 0..2047
        int il = idx >> 8, j = idx & 255;
        int ig = i0 + il;
        float av = adj[((size_t)b * NN + ig) * NN + j];
        a_t[il * 256 + j] = (j == ig) ? 0.f : av;
    }
    xs[tid] = x[((size_t)b * NN + i0) * DD + tid];
    __syncthreads();

    // ---- asum: waves 0..7, one row each
    if (tid < 512) {
        int r = tid >> 6, l = tid & 63;
        float s = a_t[r * 256 + l] + a_t[r * 256 + l + 64]
                + a_t[r * 256 + l + 128] + a_t[r * 256 + l + 192];
        #pragma unroll
        for (int m = 32; m; m >>= 1) s += __shfl_xor(s, m);
        if (l == 0) asum_s[r] = s;
    }

    // ---- pair: 64 j per thread, NO barriers in the loop
    const int dq  = tid & 31;        // d-quad
    const int row = (tid >> 5) & 7;
    const int jh  = tid >> 8;        // 0..3 (j-quarter)
    const float4 hi4 = *(const float4*)&hi[((size_t)b * NN + i0 + row) * DD + dq * 4];
    float4 acc = {0.f, 0.f, 0.f, 0.f};
    {
        const int j0 = jh * 64;
        #pragma unroll 8
        for (int jj = 0; jj < 64; ++jj) {
            const int j = j0 + jj;
            const float4 hv = *(const float4*)&hall[j * 128 + dq * 4];
            const float a = a_t[row * 256 + j];
            acc.x = fmaf(fmaxf(hi4.x + hv.x, 0.f), a, acc.x);
            acc.y = fmaf(fmaxf(hi4.y + hv.y, 0.f), a, acc.y);
            acc.z = fmaf(fmaxf(hi4.z + hv.z, 0.f), a, acc.z);
            acc.w = fmaf(fmaxf(hi4.w + hv.w, 0.f), a, acc.w);
        }
    }
    __syncthreads();       // all hall reads done before partP alias writes
    *(float4*)&partP[jh * 1024 + row * 128 + dq * 4] = acc;
    __syncthreads();
    {
        float s = partP[tid] + partP[1024 + tid] + partP[2048 + tid] + partP[3072 + tid];
        ssp[tid] = s;
    }
    __syncthreads();

    // ---- tail: 1 col/thread (dp), 8-way k-split (kg), 16 k each
    const int dp = tid & 127;
    const int kg = tid >> 7;            // 0..7
    const int kb = kg * 16;

    // stage A: agg = ssp @ w2 (+ b2*asum at combine)
    {
        float w0[16];
        #pragma unroll
        for (int k = 0; k < 16; ++k) w0[k] = w2[(kb + k) * DD + dp];
        #pragma unroll
        for (int r = 0; r < 8; ++r) {
            float a0 = 0.f;
            #pragma unroll
            for (int q = 0; q < 4; ++q) {
                const float4 sv = *(const float4*)&ssp[r * 128 + kb + q * 4];
                a0 = fmaf(sv.x, w0[q*4+0], a0);
                a0 = fmaf(sv.y, w0[q*4+1], a0);
                a0 = fmaf(sv.z, w0[q*4+2], a0);
                a0 = fmaf(sv.w, w0[q*4+3], a0);
            }
            partT[kg * 1024 + r * 128 + dp] = a0;
        }
    }
    __syncthreads();
    {
        int r = tid >> 7, d = tid & 127;
        float s = 0.f;
        #pragma unroll
        for (int w = 0; w < 8; ++w) s += partT[w * 1024 + tid];
        aggs[tid] = s + b2[d] * asum_s[r];
    }
    __syncthreads();

    // stage B: u1 = relu(x@w3a + agg@w3b + b3)
    {
        float wa0[16], wb0[16];
        #pragma unroll
        for (int k = 0; k < 16; ++k) {
            wa0[k] = w3[(kb + k) * DD + dp];
            wb0[k] = w3[(DD + kb + k) * DD + dp];
        }
        #pragma unroll
        for (int r = 0; r < 8; ++r) {
            float a0 = 0.f;
            #pragma unroll
            for (int q = 0; q < 4; ++q) {
                const float4 xv = *(const float4*)&xs[r * 128 + kb + q * 4];
                const float4 av = *(const float4*)&aggs[r * 128 + kb + q * 4];
                a0 = fmaf(xv.x, wa0[q*4+0], a0);
                a0 = fmaf(xv.y, wa0[q*4+1], a0);
                a0 = fmaf(xv.z, wa0[q*4+2], a0);
                a0 = fmaf(xv.w, wa0[q*4+3], a0);
                a0 = fmaf(av.x, wb0[q*4+0], a0);
                a0 = fmaf(av.y, wb0[q*4+1], a0);
                a0 = fmaf(av.z, wb0[q*4+2], a0);
                a0 = fmaf(av.w, wb0[q*4+3], a0);
            }
            partT[kg * 1024 + r * 128 + dp] = a0;
        }
    }
    __syncthreads();
    {
        int d = tid & 127;
        float s = 0.f;
        #pragma unroll
        for (int w = 0; w < 8; ++w) s += partT[w * 1024 + tid];
        u1s[tid] = fmaxf(s + b3[d], 0.f);
    }
    __syncthreads();

    // stage C: upd = u1 @ w4; res = x + upd + b4
    {
        float w0[16];
        #pragma unroll
        for (int k = 0; k < 16; ++k) w0[k] = w4[(kb + k) * DD + dp];
        #pragma unroll
        for (int r = 0; r < 8; ++r) {
            float a0 = 0.f;
            #pragma unroll
            for (int q = 0; q < 4; ++q) {
                const float4 uv = *(const float4*)&u1s[r * 128 + kb + q * 4];
                a0 = fmaf(uv.x, w0[q*4+0], a0);
                a0 = fmaf(uv.y, w0[q*4+1], a0);
                a0 = fmaf(uv.z, w0[q*4+2], a0);
                a0 = fmaf(uv.w, w0[q*4+3], a0);
            }
            partT[kg * 1024 + r * 128 + dp] = a0;
        }
    }
    __syncthreads();
    {
        int d = tid & 127;
        float s = xs[tid] + b4[d];
        #pragma unroll
        for (int w = 0; w < 8; ++w) s += partT[w * 1024 + tid];
        resS[tid] = s;
    }
    __syncthreads();

    // ---- LayerNorm: waves 0..7, one row each, 2 d's per lane
    if (tid < 512) {
        const int r = tid >> 6, l = tid & 63;
        const float2 v = *(const float2*)&resS[r * 128 + l * 2];
        float s1 = v.x + v.y;
        float s2 = v.x * v.x + v.y * v.y;
        #pragma unroll
        for (int m = 32; m; m >>= 1) {
            s1 += __shfl_xor(s1, m);
            s2 += __shfl_xor(s2, m);
        }
        const float mu = s1 * (1.f / DD);
        const float rs = rsqrtf(s2 * (1.f / DD) - mu * mu + LN_EPS);
        const int d = l * 2;
        const float2 gv = *(const float2*)&g[d];
        const float2 bv = *(const float2*)&bet[d];
        float2 o;
        o.x = (v.x - mu) * rs * gv.x + bv.x;
        o.y = (v.y - mu) * rs * gv.y + bv.y;
        *(float2*)&out[((size_t)b * NN + i0 + r) * DD + d] = o;
    }
}

extern "C" void kernel_launch(void* const* d_in, const int* in_sizes, int n_in,
                              void* d_out, int out_size, void* d_ws, size_t ws_size,
                              hipStream_t stream) {
    (void)in_sizes; (void)n_in; (void)out_size; (void)ws_size;
    const float* x      = (const float*)d_in[0];
    const float* adj    = (const float*)d_in[1];
    const float* msg_w1 = (const float*)d_in[2];
    const float* msg_b1 = (const float*)d_in[3];
    const float* msg_w2 = (const float*)d_in[4];
    const float* msg_b2 = (const float*)d_in[5];
    const float* upd_w1 = (const float*)d_in[6];
    const float* upd_b1 = (const float*)d_in[7];
    const float* upd_w2 = (const float*)d_in[8];
    const float* upd_b2 = (const float*)d_in[9];
    const float* ln_g   = (const float*)d_in[10];
    const float* ln_b   = (const float*)d_in[11];
    float* out = (float*)d_out;

    const size_t BND = (size_t)BB * NN * DD;
    float* ws  = (float*)d_ws;
    float* hi  = ws;            // B*N*D
    float* hjb = ws + BND;      // B*N*D

    const size_t dyn_lds = 37896 * sizeof(float);   // ~148 KB (<= 160 KB/CU)
    hipFuncSetAttribute((const void*)k_fused,
                        hipFuncAttributeMaxDynamicSharedMemorySize,
                        (int)dyn_lds);

    k_proj<<<dim3(512), dim3(512), 0, stream>>>(x, msg_w1, msg_b1, hi, hjb);
    k_fused<<<dim3(256), dim3(1024), dyn_lds, stream>>>(adj, x, hi, hjb,
                                                        msg_w2, msg_b2,
                                                        upd_w1, upd_b1,
                                                        upd_w2, upd_b2,
                                                        ln_g, ln_b, out);
}